// Round 1
// baseline (61.834 us; speedup 1.0000x reference)
//
#include <hip/hip_runtime.h>

// Problem constants (B,C,H,W = 8,1,88,128; TIMESTEPS=1000)
static constexpr int N       = 8 * 1 * 88 * 128;   // 90112 pixels
static constexpr int VEC     = 4;
static constexpr int NV      = N / VEC;            // 22528 float4 pairs
static constexpr int THREADS = 1024;               // 16 waves, one CU
static constexpr int ITERS   = NV / THREADS;       // 22, exact fit

// idx(x) = int(max(x*1000 - 1, 0)); _rn intrinsics forbid FMA contraction so
// quantization boundaries bit-match numpy's mul-then-sub (absmax was 0.0).
__device__ __forceinline__ int bucket(float x) {
    float v = __fsub_rn(__fmul_rn(x, 1000.0f), 1.0f);
    v = fmaxf(v, 0.0f);
    return (int)v;   // truncation toward zero == astype(int32) for v >= 0
}

// SINGLE block, NO workspace: the previous version's 88-block + slot-spin
// protocol forced a d_ws dependency, and the harness re-poisons the full
// 256 MiB workspace at ~40 us inside the timed region (rocprof: the top-5
// dispatches were all fillBufferAligned, WRITE_SIZE = 262144 KB). One
// 1024-thread block reads the whole 720 KB itself (~5 us on one CU),
// reduces locally, and writes the scalar. No cross-block sync at all.
__global__ __launch_bounds__(THREADS) void loss_kernel(
        const float4* __restrict__ r, const float4* __restrict__ t,
        float* __restrict__ out) {
    int c = 0;
    #pragma unroll
    for (int k = 0; k < ITERS; ++k) {
        const int i = k * THREADS + threadIdx.x;   // coalesced, exact fit
        const float4 rv = r[i];
        const float4 tv = t[i];
        c += (bucket(rv.x) != bucket(tv.x))
           + (bucket(rv.y) != bucket(tv.y))
           + (bucket(rv.z) != bucket(tv.z))
           + (bucket(rv.w) != bucket(tv.w));
    }
    // wave (64-lane) shuffle reduction
    #pragma unroll
    for (int off = 32; off > 0; off >>= 1)
        c += __shfl_down(c, off, 64);
    __shared__ int smem[THREADS / 64];   // 16 wave partials
    if ((threadIdx.x & 63) == 0) smem[threadIdx.x >> 6] = c;
    __syncthreads();
    if (threadIdx.x < 64) {
        int p = (threadIdx.x < THREADS / 64) ? smem[threadIdx.x] : 0;
        #pragma unroll
        for (int off = 8; off > 0; off >>= 1)
            p += __shfl_down(p, off, 64);
        if (threadIdx.x == 0) {
            // loss = M/(N*999) + M/N  (zero_loss + nonzero_loss), fp64 then round
            const double invN = 1.0 / (double)N;
            out[0] = (float)((double)p * (invN / 999.0 + invN));
        }
    }
}

extern "C" void kernel_launch(void* const* d_in, const int* in_sizes, int n_in,
                              void* d_out, int out_size, void* d_ws, size_t ws_size,
                              hipStream_t stream) {
    const float4* r = (const float4*)d_in[0];  // reconstructed_image, fp32
    const float4* t = (const float4*)d_in[1];  // target_image, fp32
    float* out = (float*)d_out;                // scalar fp32 loss
    (void)d_ws; (void)ws_size;                 // workspace intentionally unused

    loss_kernel<<<1, THREADS, 0, stream>>>(r, t, out);
}

// Round 2
// 55.703 us; speedup vs baseline: 1.1101x; 1.1101x over previous
//
#include <hip/hip_runtime.h>

// Problem constants (B,C,H,W = 8,1,88,128; TIMESTEPS=1000)
static constexpr int N       = 8 * 1 * 88 * 128;   // 90112 pixels
static constexpr int VEC     = 4;
static constexpr int NV      = N / VEC;            // 22528 float4 pairs
static constexpr int THREADS = 256;
static constexpr int BLOCKS  = NV / THREADS;       // 88 blocks, exact fit

// Cross-block partials live in MODULE-scope device memory, not d_ws.
// Rationale (rocprof rounds 0-1): the harness re-poisons the full 256 MiB
// workspace with a ~40 us fillBufferAligned inside the timed region
// UNCONDITIONALLY, and d_ws-based protocols forced poison-robust flag+spin
// logic that cost ~10 us of cross-XCD visibility latency. Module globals
// are never poisoned, and the dispatch boundary between the two kernels
// below provides device-scope release/acquire for free — no flags, no spin.
__device__ unsigned g_slots[BLOCKS];

// idx(x) = int(max(x*1000 - 1, 0)); _rn intrinsics forbid FMA contraction so
// quantization boundaries bit-match numpy's mul-then-sub (absmax was 0.0).
__device__ __forceinline__ int bucket(float x) {
    float v = __fsub_rn(__fmul_rn(x, 1000.0f), 1.0f);
    v = fmaxf(v, 0.0f);
    return (int)v;   // truncation toward zero == astype(int32) for v >= 0
}

// Dispatch 1: 88 blocks spread the 720 KB of HBM-cold reads over 88 CUs
// (one CU sustains only ~10 B/cyc from HBM — round 1's single-block version
// cost ~22 us for this reason). One float4-pair per thread, block-reduce,
// plain store of the 11-bit partial.
__global__ __launch_bounds__(THREADS) void partial_kernel(
        const float4* __restrict__ r, const float4* __restrict__ t) {
    const int i = blockIdx.x * THREADS + threadIdx.x;   // 0..NV-1, exact
    const float4 rv = r[i];
    const float4 tv = t[i];
    int c = (bucket(rv.x) != bucket(tv.x))
          + (bucket(rv.y) != bucket(tv.y))
          + (bucket(rv.z) != bucket(tv.z))
          + (bucket(rv.w) != bucket(tv.w));
    // wave (64-lane) shuffle reduction
    #pragma unroll
    for (int off = 32; off > 0; off >>= 1)
        c += __shfl_down(c, off, 64);
    __shared__ int smem[THREADS / 64];
    if ((threadIdx.x & 63) == 0) smem[threadIdx.x >> 6] = c;
    __syncthreads();
    if (threadIdx.x == 0)
        g_slots[blockIdx.x] = (unsigned)(smem[0] + smem[1] + smem[2] + smem[3]);
}

// Dispatch 2: one tiny block reads the 88 partials (visible via the kernel
// boundary), reduces across 2 waves, writes the scalar loss.
__global__ __launch_bounds__(128) void final_kernel(float* __restrict__ out) {
    int p = (threadIdx.x < BLOCKS) ? (int)g_slots[threadIdx.x] : 0;
    #pragma unroll
    for (int off = 32; off > 0; off >>= 1)
        p += __shfl_down(p, off, 64);
    __shared__ int smem[2];
    if ((threadIdx.x & 63) == 0) smem[threadIdx.x >> 6] = p;
    __syncthreads();
    if (threadIdx.x == 0) {
        const int M = smem[0] + smem[1];
        // loss = M/(N*999) + M/N  (zero_loss + nonzero_loss), fp64 then round
        const double invN = 1.0 / (double)N;
        out[0] = (float)((double)M * (invN / 999.0 + invN));
    }
}

extern "C" void kernel_launch(void* const* d_in, const int* in_sizes, int n_in,
                              void* d_out, int out_size, void* d_ws, size_t ws_size,
                              hipStream_t stream) {
    const float4* r = (const float4*)d_in[0];  // reconstructed_image, fp32
    const float4* t = (const float4*)d_in[1];  // target_image, fp32
    float* out = (float*)d_out;                // scalar fp32 loss
    (void)d_ws; (void)ws_size;                 // workspace intentionally unused

    partial_kernel<<<BLOCKS, THREADS, 0, stream>>>(r, t);
    final_kernel<<<1, 128, 0, stream>>>(out);
}